// Round 1
// baseline (28.087 us; speedup 1.0000x reference)
//
#include <hip/hip_runtime.h>
#include <math.h>

#define HH 512
#define WW 512
#define NN 10240
#define TILE 16
#define TXN 32              // tiles per row  (512/16)
#define TYN 32
#define NT (TXN*TYN)        // 1024 tiles
#define CAP 256             // per-tile list capacity (mean ~26 expected)
#define A_MIN (1.0f/255.0f)
#define A_MAX 0.999f

// ---------------- kernel 1: per-gaussian parameter prep ----------------
__global__ __launch_bounds__(256) void prep_kernel(
    const float* __restrict__ xyz, const float* __restrict__ chol,
    const float* __restrict__ opac, const float* __restrict__ feat,
    float4* __restrict__ P0, float4* __restrict__ P1, float4* __restrict__ P2) {
  int n = blockIdx.x * 256 + threadIdx.x;
  if (n >= NN) return;
  float mx = tanhf(xyz[2*n+0]);
  float my = tanhf(xyz[2*n+1]);
  float cx = 0.5f * WW * (mx + 1.0f);
  float cy = 0.5f * HH * (my + 1.0f);
  float l1 = chol[3*n+0] + 0.5f;
  float l2 = chol[3*n+1];
  float l3 = chol[3*n+2] + 0.5f;
  float c00 = l1*l1;
  float c01 = l1*l2;
  float c11 = l2*l2 + l3*l3;
  float det = c00*c11 - c01*c01;      // = l1^2 * l3^2 > 0 always
  float inv = 1.0f / det;
  float A = c11 * inv;
  float B = -c01 * inv;
  float C = c00 * inv;
  float op = opac[n];
  // support: alpha = op*exp(-sigma) >= 1/255  =>  sigma <= log(255*op)
  float smax = logf(op * 255.0f);     // op==0 -> -inf, handled below
  float rx = -1.0f, ry = -1.0f;
  if (smax > 0.0f) {
    rx = sqrtf(2.0f * smax * c00) + 1.0f;   // +1 px safety margin
    ry = sqrtf(2.0f * smax * c11) + 1.0f;
  }
  P0[n] = make_float4(cx, cy, A, B);
  P1[n] = make_float4(C, op, feat[3*n+0], feat[3*n+1]);
  P2[n] = make_float4(feat[3*n+2], rx, ry, 0.0f);
}

// ---------------- kernel 2: bin gaussians into 16x16 tiles ----------------
__global__ __launch_bounds__(256) void bin_kernel(
    const float4* __restrict__ P0, const float4* __restrict__ P2,
    int* __restrict__ counts, int* __restrict__ lists) {
  int n = blockIdx.x * 256 + threadIdx.x;
  if (n >= NN) return;
  float4 p2 = P2[n];
  float rx = p2.y, ry = p2.z;
  if (rx < 0.0f) return;                      // culled (invisible)
  float4 p0 = P0[n];
  float cx = p0.x, cy = p0.y;
  int px0 = max(0,    (int)floorf(cx - rx));
  int px1 = min(WW-1, (int)floorf(cx + rx));
  int py0 = max(0,    (int)floorf(cy - ry));
  int py1 = min(HH-1, (int)floorf(cy + ry));
  if (px0 > px1 || py0 > py1) return;
  int tx0 = px0 >> 4, tx1 = px1 >> 4;
  int ty0 = py0 >> 4, ty1 = py1 >> 4;
  for (int ty = ty0; ty <= ty1; ++ty)
    for (int tx = tx0; tx <= tx1; ++tx) {
      int t = ty * TXN + tx;
      int idx = atomicAdd(&counts[t], 1);
      if (idx < CAP) lists[t * CAP + idx] = n;
    }
}

// ---------------- kernel 3: per-tile gather render ----------------
__global__ __launch_bounds__(256) void render_kernel(
    const float4* __restrict__ P0, const float4* __restrict__ P1,
    const float4* __restrict__ P2,
    const int* __restrict__ counts, const int* __restrict__ lists,
    float* __restrict__ out) {
  __shared__ float4 s0[256];
  __shared__ float4 s1[256];
  __shared__ float  sb[256];

  int tx = blockIdx.x, ty = blockIdx.y;
  int t  = ty * TXN + tx;
  int lx = threadIdx.x & 15;
  int ly = threadIdx.x >> 4;
  int x = tx * TILE + lx;
  int y = ty * TILE + ly;
  float px = x + 0.5f;
  float py = y + 0.5f;

  int cnt = min(counts[t], CAP);
  float accR = 0.0f, accG = 0.0f, accB = 0.0f;

  for (int base = 0; base < cnt; base += 256) {
    __syncthreads();
    int m = min(256, cnt - base);
    if ((int)threadIdx.x < m) {
      int n = lists[t * CAP + base + threadIdx.x];
      s0[threadIdx.x] = P0[n];
      s1[threadIdx.x] = P1[n];
      sb[threadIdx.x] = P2[n].x;
    }
    __syncthreads();
    for (int j = 0; j < m; ++j) {
      float4 p0 = s0[j];            // cx, cy, A, B  (LDS broadcast)
      float4 p1 = s1[j];            // C, op, r, g
      float dx = p0.x - px;
      float dy = p0.y - py;
      float sigma = 0.5f * p0.z * dx * dx
                  + 0.5f * p1.x * dy * dy
                  + p0.w * dy * dx;
      float alpha = fminf(A_MAX, p1.y * __expf(-sigma));
      if (sigma >= 0.0f && alpha >= A_MIN) {
        accR += alpha * p1.z;
        accG += alpha * p1.w;
        accB += alpha * sb[j];
      }
    }
  }

  int pix = y * WW + x;
  out[0 * HH * WW + pix] = fminf(fmaxf(accR, 0.0f), 1.0f);
  out[1 * HH * WW + pix] = fminf(fmaxf(accG, 0.0f), 1.0f);
  out[2 * HH * WW + pix] = fminf(fmaxf(accB, 0.0f), 1.0f);
}

// ---------------- launcher ----------------
extern "C" void kernel_launch(void* const* d_in, const int* in_sizes, int n_in,
                              void* d_out, int out_size, void* d_ws, size_t ws_size,
                              hipStream_t stream) {
  const float* xyz  = (const float*)d_in[0];   // (N,2)
  const float* chol = (const float*)d_in[1];   // (N,3)
  const float* opac = (const float*)d_in[2];   // (N,1)
  const float* feat = (const float*)d_in[3];   // (N,3)

  char* ws = (char*)d_ws;
  float4* P0    = (float4*)(ws);
  float4* P1    = (float4*)(ws + (size_t)NN * 16);
  float4* P2    = (float4*)(ws + (size_t)NN * 32);
  int*    counts= (int*)   (ws + (size_t)NN * 48);
  int*    lists = (int*)   (ws + (size_t)NN * 48 + NT * sizeof(int));
  // total ws use: 491520 + 4096 + 1048576 ≈ 1.5 MB

  hipMemsetAsync(counts, 0, NT * sizeof(int), stream);
  prep_kernel<<<(NN + 255) / 256, 256, 0, stream>>>(xyz, chol, opac, feat, P0, P1, P2);
  bin_kernel<<<(NN + 255) / 256, 256, 0, stream>>>(P0, P2, counts, lists);
  render_kernel<<<dim3(TXN, TYN), 256, 0, stream>>>(P0, P1, P2, counts, lists, (float*)d_out);
}